// Round 19
// baseline (44.071 us; speedup 1.0000x reference)
//
#include <hip/hip_runtime.h>

#define CIN   32
#define COUT  64
#define HH    64
#define WW    64
#define NB    4
#define TH    8              // rows per block
#define HR    (TH + 2)       // 10 staged rows
#define G     4              // input channels per LDS round (small -> 8 blocks/CU fit)
#define ROWCI 72             // dwords per (row, ci): two 36-dword parity arrays
#define WPK   20             // padded dwords per ci weight pack: [A 9 | pad | C 9 | pad]
// parity array layout (36 dwords): [0]=left halo (col -1), [1..32]=cols, [33]=right halo (col 64)

// ---- VOP3P packed-f32 helpers (CDNA4: v_pk_* = 2 fp32 ops/inst) ----
__device__ __forceinline__ float2 pk_fma_(float2 a, float2 b, float2 c) {   // a*b+c per half
    float2 d;
    asm("v_pk_fma_f32 %0, %1, %2, %3" : "=v"(d) : "v"(a), "v"(b), "v"(c));
    return d;
}
__device__ __forceinline__ float2 pk_add_(float2 a, float2 b) {
    float2 d;
    asm("v_pk_add_f32 %0, %1, %2" : "=v"(d) : "v"(a), "v"(b));
    return d;
}
template<int HI>        // a * {b[HI],b[HI]} : broadcast one half of pair b via op_sel
__device__ __forceinline__ float2 pk_mul_sel(float2 a, float2 b) {
    float2 d;
    if (HI) asm("v_pk_mul_f32 %0, %1, %2 op_sel:[0,1] op_sel_hi:[1,1]" : "=v"(d) : "v"(a), "v"(b));
    else    asm("v_pk_mul_f32 %0, %1, %2 op_sel:[0,0] op_sel_hi:[1,0]" : "=v"(d) : "v"(a), "v"(b));
    return d;
}
template<int HI>        // a * {b[HI],b[HI]} + c
__device__ __forceinline__ float2 pk_fma_sel(float2 a, float2 b, float2 c) {
    float2 d;
    if (HI) asm("v_pk_fma_f32 %0, %1, %2, %3 op_sel:[0,1,0] op_sel_hi:[1,1,1]" : "=v"(d) : "v"(a), "v"(b), "v"(c));
    else    asm("v_pk_fma_f32 %0, %1, %2, %3 op_sel:[0,0,0] op_sel_hi:[1,0,1]" : "=v"(d) : "v"(a), "v"(b), "v"(c));
    return d;
}

template<int S>
__device__ __forceinline__ void math_g(const float* __restrict__ sx,
                                       const float* __restrict__ sw,
                                       int lrow, int m, int cb, int g,
                                       float2& aeg2, float2& cv2)
{
    #pragma unroll 2
    for (int cl = 0; cl < G; ++cl) {
        const int ci = g + cl;
        // 15 taps: 5 window rows x (center b32 + side pair -> ds_read2_b32)
        float tc[5], tl[5], tr[5];
        #pragma unroll
        for (int wr = 0; wr < 5; ++wr) {
            const int qc = (wr & 1) ^ 1 ^ S;              // compile-time array select
            const float* rowp = sx + (lrow + wr) * (G * ROWCI) + cl * ROWCI;
            tc[wr] = rowp[qc * 36 + 1 + m];
            const float* sp = rowp + (1 - qc) * 36 + m + cb;
            tl[wr] = sp[0];
            tr[wr] = sp[1];
        }
        // pixel-pair taps: lo = p0 (window rows 0..2), hi = p1 (window rows 2..4)
        float2 t2c[3], t2l[3], t2r[3];
        #pragma unroll
        for (int wr = 0; wr < 3; ++wr) {
            t2c[wr] = make_float2(tc[wr], tc[wr + 2]);
            t2l[wr] = make_float2(tl[wr], tl[wr + 2]);
            t2r[wr] = make_float2(tr[wr], tr[wr + 2]);
        }

        // weights for this block's single co: 5 x ds_read_b128 broadcast (20-dword pack)
        float w[WPK];
        const float* pw = sw + ci * WPK;
        #pragma unroll
        for (int u = 0; u < 5; ++u)
            *(float4*)&w[4 * u] = *(const float4*)&pw[4 * u];
        const float2* w2 = (const float2*)w;

        float2 r2 = make_float2(0.0f, 0.0f);
        #pragma unroll
        for (int k = 0; k < 9; ++k) {
            const int wr = k / 3;
            const int kj = k % 3;
            const float2 t2 = (kj == 0) ? t2l[wr] : ((kj == 1) ? t2c[wr] : t2r[wr]);
            const int ia = k;               // A[k] at dword k
            const int ic = 10 + k;          // C[k] at dword 10+k
            float2 prod = (ia & 1) ? pk_mul_sel<1>(t2, w2[ia / 2])
                                   : pk_mul_sel<0>(t2, w2[ia / 2]);
            // pixel parity == S -> step parity = S^(k&1); even: r=(r+t)*y = r*y+prod
            //                                             odd : r=(r+y)*t = r*t+prod
            if ((k & 1) == S)
                r2 = (ia & 1) ? pk_fma_sel<1>(r2, w2[ia / 2], prod)
                              : pk_fma_sel<0>(r2, w2[ia / 2], prod);
            else
                r2 = pk_fma_(r2, t2, prod);
            cv2 = (ic & 1) ? pk_fma_sel<1>(t2, w2[ic / 2], cv2)
                           : pk_fma_sel<0>(t2, w2[ic / 2], cv2);
        }
        aeg2 = pk_add_(aeg2, r2);
    }
}

__global__ __launch_bounds__(256, 8)
void aeg_conv_kernel(const float* __restrict__ x,
                     const float* __restrict__ weight,
                     const float* __restrict__ conv_w,
                     const float* __restrict__ conv_b,
                     float* __restrict__ out)
{
    __shared__ float sx[HR * G * ROWCI];          // 10*4*72*4 = 11520 B
    __shared__ float sw[CIN * WPK];               // 32*20*4   = 2560 B

    const int tid = threadIdx.x;
    const int i0  = blockIdx.x * TH;
    const int n   = blockIdx.y;
    const int co  = blockIdx.z;                   // one output channel per block

    const int s  = (tid >> 6) & 1;      // wave parity class (wave-uniform)
    const int rg = tid >> 7;            // row group (0,1)
    const int h  = (tid >> 5) & 1;      // half-wave -> row offset
    const int m  = tid & 31;

    const int rb_local = rg * 4 + h;            // local first pixel row: {0,1,4,5}; owns +0,+2
    const int rb  = i0 + rb_local;              // absolute first pixel row
    const int cb  = (rb & 1) ^ s;               // column LSB for this lane's class
    const int col = 2 * m + cb;                 // owned column (both pixel rows)

    const float* xn = x + (size_t)n * (CIN * HH * WW);

    // ---- zero the halo-column slots (0 and 33) of every parity array, once ----
    for (int idx = tid; idx < HR * G * 2 * 2; idx += 256) {
        int arr  = idx >> 1;                    // 0..79
        int slot = (idx & 1) ? 33 : 0;
        sx[arr * 36 + slot] = 0.0f;
    }

    // ---- stage this co's weight pack into LDS: [ci][A 9 | 0 | C 9 | 0] ----
    for (int idx = tid; idx < CIN * WPK; idx += 256) {
        int ci = idx / WPK, slot = idx - ci * WPK;
        float v = 0.0f;
        if (slot < 9)                    v = weight[((size_t)co * CIN + ci) * 9 + slot];
        else if (slot >= 10 && slot < 19) v = conv_w[((size_t)co * CIN + ci) * 9 + (slot - 10)];
        sw[idx] = v;
    }

    float2 aeg2 = make_float2(0.0f, 0.0f);
    float2 cv2  = make_float2(0.0f, 0.0f);

    for (int g = 0; g < CIN; g += G) {
        __syncthreads();                // previous readers done (also covers init writes)
        // ---- stage HR rows x G ci, parity-split: scalar b32 stores (R14 known-good) ----
        #pragma unroll
        for (int it = 0; it < 3; ++it) {
            int idx = it * 256 + tid;           // 0..767, need 640
            if (idx < HR * G * 16) {
                int f4   = idx & 15;            // 16B chunk within row
                int pair = idx >> 4;            // r10*G + cl, 0..39
                int r10  = pair >> 2;
                int cl   = pair & 3;
                int gi   = i0 - 1 + r10;
                float4 v = make_float4(0.f, 0.f, 0.f, 0.f);
                if ((unsigned)gi < (unsigned)HH)
                    v = *(const float4*)&xn[(g + cl) * (HH * WW) + gi * WW + 4 * f4];
                int rp   = gi & 1;              // parity array holding even cols
                float* base = &sx[pair * ROWCI];
                base[rp * 36 + 1 + 2 * f4]        = v.x;   // col 4f4
                base[rp * 36 + 2 + 2 * f4]        = v.z;   // col 4f4+2
                base[(rp ^ 1) * 36 + 1 + 2 * f4]  = v.y;   // col 4f4+1
                base[(rp ^ 1) * 36 + 2 + 2 * f4]  = v.w;   // col 4f4+3
            }
        }
        __syncthreads();

        if (s == 0) math_g<0>(sx, sw, rb_local, m, cb, g, aeg2, cv2);
        else        math_g<1>(sx, sw, rb_local, m, cb, g, aeg2, cv2);
    }

    // ---- epilogue: sigmoid(aeg) * (conv + bias) ----
    const float bias = conv_b[co];
    #pragma unroll
    for (int p = 0; p < 2; ++p) {
        int i = rb + 2 * p;
        float a = p ? aeg2.y : aeg2.x;
        float v = p ? cv2.y  : cv2.x;
        float conv = v + bias;
        float sg = 1.0f / (1.0f + __expf(-a));
        out[(((size_t)n * COUT + co) * HH + i) * WW + col] = sg * conv;
    }
}

extern "C" void kernel_launch(void* const* d_in, const int* in_sizes, int n_in,
                              void* d_out, int out_size, void* d_ws, size_t ws_size,
                              hipStream_t stream) {
    const float* x      = (const float*)d_in[0];
    const float* weight = (const float*)d_in[1];
    const float* conv_w = (const float*)d_in[2];
    const float* conv_b = (const float*)d_in[3];
    float* out = (float*)d_out;

    dim3 grid(HH / TH, NB, COUT);   // 8 x 4 x 64 = 2048 blocks -> 8 blocks/CU, 32 waves/CU
    aeg_conv_kernel<<<grid, 256, 0, stream>>>(x, weight, conv_w, conv_b, out);
}

// Round 20
// 38.601 us; speedup vs baseline: 1.1417x; 1.1417x over previous
//
#include <hip/hip_runtime.h>

#define CIN   32
#define COUT  64
#define HH    64
#define WW    64
#define NB    4
#define TH    8              // rows per block
#define CPT   2              // output channels per thread
// packed weight LDS: sw[ci][36] = [A(co0) 9 | A(co1) 9 | C(co0) 9 | C(co1) 9]
// taps: register-resident. lane m loads cols {2m,2m+1} per window row (coalesced dwordx2);
// the missing side column comes from the neighbor lane via one ds_bpermute per row.

// ---- VOP3P packed-f32 helpers (CDNA4: v_pk_* = 2 fp32 ops/inst) ----
__device__ __forceinline__ float2 pk_fma_(float2 a, float2 b, float2 c) {   // a*b+c per half
    float2 d;
    asm("v_pk_fma_f32 %0, %1, %2, %3" : "=v"(d) : "v"(a), "v"(b), "v"(c));
    return d;
}
__device__ __forceinline__ float2 pk_add_(float2 a, float2 b) {
    float2 d;
    asm("v_pk_add_f32 %0, %1, %2" : "=v"(d) : "v"(a), "v"(b));
    return d;
}
template<int HI>        // a * {b[HI],b[HI]} : broadcast one half of pair b via op_sel
__device__ __forceinline__ float2 pk_mul_sel(float2 a, float2 b) {
    float2 d;
    if (HI) asm("v_pk_mul_f32 %0, %1, %2 op_sel:[0,1] op_sel_hi:[1,1]" : "=v"(d) : "v"(a), "v"(b));
    else    asm("v_pk_mul_f32 %0, %1, %2 op_sel:[0,0] op_sel_hi:[1,0]" : "=v"(d) : "v"(a), "v"(b));
    return d;
}
template<int HI>        // a * {b[HI],b[HI]} + c
__device__ __forceinline__ float2 pk_fma_sel(float2 a, float2 b, float2 c) {
    float2 d;
    if (HI) asm("v_pk_fma_f32 %0, %1, %2, %3 op_sel:[0,1,0] op_sel_hi:[1,1,1]" : "=v"(d) : "v"(a), "v"(b), "v"(c));
    else    asm("v_pk_fma_f32 %0, %1, %2, %3 op_sel:[0,0,0] op_sel_hi:[1,0,1]" : "=v"(d) : "v"(a), "v"(b), "v"(c));
    return d;
}

template<int S>
__device__ __forceinline__ void ci_math(const float tc[5], const float tl[5], const float tr[5],
                                        const float* __restrict__ sw, int ci,
                                        float2 aeg2[CPT], float2 cv2[CPT])
{
    // pixel-pair taps: lo = p0 (window rows 0..2), hi = p1 (window rows 2..4)
    float2 t2c[3], t2l[3], t2r[3];
    #pragma unroll
    for (int wr = 0; wr < 3; ++wr) {
        t2c[wr] = make_float2(tc[wr], tc[wr + 2]);
        t2l[wr] = make_float2(tl[wr], tl[wr + 2]);
        t2r[wr] = make_float2(tr[wr], tr[wr + 2]);
    }

    // packed weights: 9 x ds_read_b128 broadcast (same-address -> cheap)
    float w[36];
    const float* pw = sw + ci * 36;
    #pragma unroll
    for (int u = 0; u < 9; ++u)
        *(float4*)&w[4 * u] = *(const float4*)&pw[4 * u];
    const float2* w2 = (const float2*)w;

    #pragma unroll
    for (int c = 0; c < CPT; ++c) {
        float2 r2 = make_float2(0.0f, 0.0f);
        #pragma unroll
        for (int k = 0; k < 9; ++k) {
            const int wr = k / 3;
            const int kj = k % 3;
            const float2 t2 = (kj == 0) ? t2l[wr] : ((kj == 1) ? t2c[wr] : t2r[wr]);
            const int ia = c * 9 + k;           // wA[k] at w2[ia/2][ia&1]
            const int ic = 18 + c * 9 + k;      // wC[k]
            float2 prod = (ia & 1) ? pk_mul_sel<1>(t2, w2[ia / 2])
                                   : pk_mul_sel<0>(t2, w2[ia / 2]);
            // pixel parity == S -> step parity = S^(k&1); even: r=(r+t)*y = r*y+prod
            //                                             odd : r=(r+y)*t = r*t+prod
            if ((k & 1) == S)
                r2 = (ia & 1) ? pk_fma_sel<1>(r2, w2[ia / 2], prod)
                              : pk_fma_sel<0>(r2, w2[ia / 2], prod);
            else
                r2 = pk_fma_(r2, t2, prod);
            cv2[c] = (ic & 1) ? pk_fma_sel<1>(t2, w2[ic / 2], cv2[c])
                              : pk_fma_sel<0>(t2, w2[ic / 2], cv2[c]);
        }
        aeg2[c] = pk_add_(aeg2[c], r2);
    }
}

template<int S>
__device__ __forceinline__ void math_all(const float* __restrict__ xn,
                                         const float* __restrict__ sw,
                                         const int rowOff[5], const bool vr[5],
                                         int pidx, bool zside, int cb,
                                         float2 aeg2[CPT], float2 cv2[CPT])
{
    #pragma unroll 2
    for (int ci = 0; ci < CIN; ++ci) {
        const float* pci = xn + ci * (HH * WW);
        float tc[5], tl[5], tr[5];
        #pragma unroll
        for (int wr = 0; wr < 5; ++wr) {
            float2 v = *(const float2*)(pci + rowOff[wr]);   // clamped row, always in-bounds
            v.x = vr[wr] ? v.x : 0.0f;                        // zero out-of-image rows
            v.y = vr[wr] ? v.y : 0.0f;
            // neighbor's needed half: cb=0 lanes give hi to the right puller is wrong way --
            // each lane CONTRIBUTES what its same-cb neighbor wants: cb ? lo : hi
            float contrib = cb ? v.x : v.y;
            float side = __int_as_float(__builtin_amdgcn_ds_bpermute(pidx, __float_as_int(contrib)));
            side = zside ? 0.0f : side;                       // image border column
            tl[wr] = cb ? v.x : side;
            tc[wr] = cb ? v.y : v.x;
            tr[wr] = cb ? side : v.y;
        }
        ci_math<S>(tc, tl, tr, sw, ci, aeg2, cv2);
    }
}

__global__ __launch_bounds__(256, 4)
void aeg_conv_kernel(const float* __restrict__ x,
                     const float* __restrict__ weight,
                     const float* __restrict__ conv_w,
                     const float* __restrict__ conv_b,
                     float* __restrict__ out)
{
    __shared__ float sw[CIN * 36];                // 4608 B only

    const int tid = threadIdx.x;
    const int i0  = blockIdx.x * TH;
    const int n   = blockIdx.y;
    const int co0 = blockIdx.z * CPT;

    const int s  = (tid >> 6) & 1;      // wave parity class (wave-uniform)
    const int rg = tid >> 7;            // row group (0,1)
    const int h  = (tid >> 5) & 1;      // half-wave -> row offset
    const int m  = tid & 31;

    const int rb_local = rg * 4 + h;            // local first pixel row: {0,1,4,5}; owns +0,+2
    const int rb  = i0 + rb_local;              // absolute first pixel row
    const int cb  = (rb & 1) ^ s;               // column LSB for this lane's class
    const int col = 2 * m + cb;                 // owned column (both pixel rows)

    const float* xn = x + (size_t)n * (CIN * HH * WW);

    // ---- stage packed weight slice into LDS: [ci][A0|A1|C0|C1] ----
    for (int idx = tid; idx < CIN * 36; idx += 256) {
        int ci = idx / 36, slot = idx - ci * 36;
        int set = slot / 18, rem = slot - set * 18;
        int c2 = rem / 9, k = rem - c2 * 9;
        const float* src = set ? conv_w : weight;
        sw[idx] = src[((size_t)(co0 + c2) * CIN + ci) * 9 + k];
    }
    __syncthreads();                    // the only barrier in the kernel

    // ---- per-lane window-row geometry (5 rows: rb-1 .. rb+3) ----
    int rowOff[5]; bool vr[5];
    #pragma unroll
    for (int wr = 0; wr < 5; ++wr) {
        int gi = rb - 1 + wr;
        vr[wr] = (unsigned)gi < (unsigned)HH;
        int gc = gi < 0 ? 0 : (gi > HH - 1 ? HH - 1 : gi);
        rowOff[wr] = gc * WW + 2 * m;
    }
    const bool zside = cb ? (m == 31) : (m == 0);           // side tap is image border -> 0
    const int  pidx  = (((tid & 63) + (cb ? 1 : 63)) & 63) * 4;   // neighbor lane (+-1) * 4

    float2 aeg2[CPT], cv2[CPT];
    #pragma unroll
    for (int c = 0; c < CPT; ++c) {
        aeg2[c] = make_float2(0.0f, 0.0f);
        cv2[c]  = make_float2(0.0f, 0.0f);
    }

    if (s == 0) math_all<0>(xn, sw, rowOff, vr, pidx, zside, cb, aeg2, cv2);
    else        math_all<1>(xn, sw, rowOff, vr, pidx, zside, cb, aeg2, cv2);

    // ---- epilogue: sigmoid(aeg) * (conv + bias) ----
    #pragma unroll
    for (int p = 0; p < 2; ++p) {
        int i = rb + 2 * p;
        #pragma unroll
        for (int c = 0; c < CPT; ++c) {
            int co = co0 + c;
            float a = p ? aeg2[c].y : aeg2[c].x;
            float v = p ? cv2[c].y  : cv2[c].x;
            float conv = v + conv_b[co];
            float sg = 1.0f / (1.0f + __expf(-a));
            out[(((size_t)n * COUT + co) * HH + i) * WW + col] = sg * conv;
        }
    }
}

extern "C" void kernel_launch(void* const* d_in, const int* in_sizes, int n_in,
                              void* d_out, int out_size, void* d_ws, size_t ws_size,
                              hipStream_t stream) {
    const float* x      = (const float*)d_in[0];
    const float* weight = (const float*)d_in[1];
    const float* conv_w = (const float*)d_in[2];
    const float* conv_b = (const float*)d_in[3];
    float* out = (float*)d_out;

    dim3 grid(HH / TH, NB, COUT / CPT);   // 8 x 4 x 32 = 1024 blocks
    aeg_conv_kernel<<<grid, 256, 0, stream>>>(x, weight, conv_w, conv_b, out);
}

// Round 21
// 33.573 us; speedup vs baseline: 1.3127x; 1.1498x over previous
//
#include <hip/hip_runtime.h>

#define CIN   32
#define COUT  64
#define HH    64
#define WW    64
#define NB    4
#define TH    8              // rows per block
#define HR    (TH + 2)       // 10 staged rows
#define G     8              // input channels per LDS round
#define CPT   2              // output channels per thread
#define ROWCI 72             // dwords per (row, ci): two 36-dword parity arrays
// parity array layout (36 dwords): [0]=left halo (col -1), [1..32]=cols, [33]=right halo (col 64)
// packed weight LDS: sw[ci][36] = [A(co0) 9 | A(co1) 9 | C(co0) 9 | C(co1) 9]

// ---- VOP3P packed-f32 helpers (CDNA4: v_pk_* = 2 fp32 ops/inst) ----
__device__ __forceinline__ float2 pk_fma_(float2 a, float2 b, float2 c) {   // a*b+c per half
    float2 d;
    asm("v_pk_fma_f32 %0, %1, %2, %3" : "=v"(d) : "v"(a), "v"(b), "v"(c));
    return d;
}
__device__ __forceinline__ float2 pk_add_(float2 a, float2 b) {
    float2 d;
    asm("v_pk_add_f32 %0, %1, %2" : "=v"(d) : "v"(a), "v"(b));
    return d;
}
template<int HI>        // a * {b[HI],b[HI]} : broadcast one half of pair b via op_sel
__device__ __forceinline__ float2 pk_mul_sel(float2 a, float2 b) {
    float2 d;
    if (HI) asm("v_pk_mul_f32 %0, %1, %2 op_sel:[0,1] op_sel_hi:[1,1]" : "=v"(d) : "v"(a), "v"(b));
    else    asm("v_pk_mul_f32 %0, %1, %2 op_sel:[0,0] op_sel_hi:[1,0]" : "=v"(d) : "v"(a), "v"(b));
    return d;
}
template<int HI>        // a * {b[HI],b[HI]} + c
__device__ __forceinline__ float2 pk_fma_sel(float2 a, float2 b, float2 c) {
    float2 d;
    if (HI) asm("v_pk_fma_f32 %0, %1, %2, %3 op_sel:[0,1,0] op_sel_hi:[1,1,1]" : "=v"(d) : "v"(a), "v"(b), "v"(c));
    else    asm("v_pk_fma_f32 %0, %1, %2, %3 op_sel:[0,0,0] op_sel_hi:[1,0,1]" : "=v"(d) : "v"(a), "v"(b), "v"(c));
    return d;
}

template<int S>
__device__ __forceinline__ void math_g(const float* __restrict__ sx,
                                       const float* __restrict__ sw,
                                       int lrow, int m, int cb, int g,
                                       float2 aeg2[CPT], float2 cv2[CPT])
{
    #pragma unroll 2
    for (int cl = 0; cl < G; ++cl) {
        const int ci = g + cl;
        // 15 taps: 5 window rows x (center b32 + side pair -> ds_read2_b32)
        float tc[5], tl[5], tr[5];
        #pragma unroll
        for (int wr = 0; wr < 5; ++wr) {
            const int qc = (wr & 1) ^ 1 ^ S;              // compile-time array select
            const float* rowp = sx + (lrow + wr) * (G * ROWCI) + cl * ROWCI;
            tc[wr] = rowp[qc * 36 + 1 + m];
            const float* sp = rowp + (1 - qc) * 36 + m + cb;
            tl[wr] = sp[0];
            tr[wr] = sp[1];
        }
        // pixel-pair taps: lo = p0 (window rows 0..2), hi = p1 (window rows 2..4)
        float2 t2c[3], t2l[3], t2r[3];
        #pragma unroll
        for (int wr = 0; wr < 3; ++wr) {
            t2c[wr] = make_float2(tc[wr], tc[wr + 2]);
            t2l[wr] = make_float2(tl[wr], tl[wr + 2]);
            t2r[wr] = make_float2(tr[wr], tr[wr + 2]);
        }

        // packed weights: 9 x ds_read_b128 broadcast; view as float2 pairs for op_sel
        float w[36];
        const float* pw = sw + ci * 36;
        #pragma unroll
        for (int u = 0; u < 9; ++u)
            *(float4*)&w[4 * u] = *(const float4*)&pw[4 * u];
        const float2* w2 = (const float2*)w;

        #pragma unroll
        for (int c = 0; c < CPT; ++c) {
            float2 r2 = make_float2(0.0f, 0.0f);
            #pragma unroll
            for (int k = 0; k < 9; ++k) {
                const int wr = k / 3;
                const int kj = k % 3;
                const float2 t2 = (kj == 0) ? t2l[wr] : ((kj == 1) ? t2c[wr] : t2r[wr]);
                const int ia = c * 9 + k;           // wA[k] at w2[ia/2][ia&1]
                const int ic = 18 + c * 9 + k;      // wC[k]
                float2 prod = (ia & 1) ? pk_mul_sel<1>(t2, w2[ia / 2])
                                       : pk_mul_sel<0>(t2, w2[ia / 2]);
                // pixel parity == S -> step parity = S^(k&1); even: r=(r+t)*y = r*y+prod
                //                                             odd : r=(r+y)*t = r*t+prod
                if ((k & 1) == S)
                    r2 = (ia & 1) ? pk_fma_sel<1>(r2, w2[ia / 2], prod)
                                  : pk_fma_sel<0>(r2, w2[ia / 2], prod);
                else
                    r2 = pk_fma_(r2, t2, prod);
                cv2[c] = (ic & 1) ? pk_fma_sel<1>(t2, w2[ic / 2], cv2[c])
                                  : pk_fma_sel<0>(t2, w2[ic / 2], cv2[c]);
            }
            aeg2[c] = pk_add_(aeg2[c], r2);
        }
    }
}

__global__ __launch_bounds__(256, 4)
void aeg_conv_kernel(const float* __restrict__ x,
                     const float* __restrict__ weight,
                     const float* __restrict__ conv_w,
                     const float* __restrict__ conv_b,
                     float* __restrict__ out)
{
    __shared__ float sx[HR * G * ROWCI];          // 10*8*72*4 = 23040 B
    __shared__ float sw[CIN * 36];                // 32*36*4   = 4608 B

    const int tid = threadIdx.x;
    const int i0  = blockIdx.x * TH;
    const int n   = blockIdx.y;
    const int co0 = blockIdx.z * CPT;

    const int s  = (tid >> 6) & 1;      // wave parity class (wave-uniform)
    const int rg = tid >> 7;            // row group (0,1)
    const int h  = (tid >> 5) & 1;      // half-wave -> row offset
    const int m  = tid & 31;

    const int rb_local = rg * 4 + h;            // local first pixel row: {0,1,4,5}; owns +0,+2
    const int rb  = i0 + rb_local;              // absolute first pixel row
    const int cb  = (rb & 1) ^ s;               // column LSB for this lane's class
    const int col = 2 * m + cb;                 // owned column (both pixel rows)

    const float* xn = x + (size_t)n * (CIN * HH * WW);

    // ---- zero the halo-column slots (0 and 33) of every parity array, once ----
    for (int idx = tid; idx < HR * G * 2 * 2; idx += 256) {
        int arr  = idx >> 1;                    // 0..159
        int slot = (idx & 1) ? 33 : 0;
        sx[arr * 36 + slot] = 0.0f;
    }

    // ---- stage packed weight slice into LDS: [ci][A0|A1|C0|C1] ----
    for (int idx = tid; idx < CIN * 36; idx += 256) {
        int ci = idx / 36, slot = idx - ci * 36;
        int set = slot / 18, rem = slot - set * 18;
        int c2 = rem / 9, k = rem - c2 * 9;
        const float* src = set ? conv_w : weight;
        sw[idx] = src[((size_t)(co0 + c2) * CIN + ci) * 9 + k];
    }

    float2 aeg2[CPT], cv2[CPT];
    #pragma unroll
    for (int c = 0; c < CPT; ++c) {
        aeg2[c] = make_float2(0.0f, 0.0f);
        cv2[c]  = make_float2(0.0f, 0.0f);
    }

    for (int g = 0; g < CIN; g += G) {
        __syncthreads();                // previous readers done (also covers init writes)
        // ---- stage HR rows x G ci, parity-split: scalar b32 stores (known-good) ----
        #pragma unroll
        for (int it = 0; it < 5; ++it) {
            int idx  = it * 256 + tid;          // 0..1279
            int f4   = idx & 15;                // 16B chunk within row
            int pair = idx >> 4;                // r10*G + cl, 0..79
            int r10  = pair >> 3;
            int cl   = pair & 7;
            int gi   = i0 - 1 + r10;
            float4 v = make_float4(0.f, 0.f, 0.f, 0.f);
            if ((unsigned)gi < (unsigned)HH)
                v = *(const float4*)&xn[(g + cl) * (HH * WW) + gi * WW + 4 * f4];
            int rp   = gi & 1;                  // parity array holding even cols
            float* base = &sx[pair * ROWCI];
            base[rp * 36 + 1 + 2 * f4]        = v.x;   // col 4f4
            base[rp * 36 + 2 + 2 * f4]        = v.z;   // col 4f4+2
            base[(rp ^ 1) * 36 + 1 + 2 * f4]  = v.y;   // col 4f4+1
            base[(rp ^ 1) * 36 + 2 + 2 * f4]  = v.w;   // col 4f4+3
        }
        __syncthreads();

        if (s == 0) math_g<0>(sx, sw, rb_local, m, cb, g, aeg2, cv2);
        else        math_g<1>(sx, sw, rb_local, m, cb, g, aeg2, cv2);
    }

    // ---- epilogue: sigmoid(aeg) * (conv + bias) ----
    #pragma unroll
    for (int p = 0; p < 2; ++p) {
        int i = rb + 2 * p;
        #pragma unroll
        for (int c = 0; c < CPT; ++c) {
            int co = co0 + c;
            float a = p ? aeg2[c].y : aeg2[c].x;
            float v = p ? cv2[c].y  : cv2[c].x;
            float conv = v + conv_b[co];
            float sg = 1.0f / (1.0f + __expf(-a));
            out[(((size_t)n * COUT + co) * HH + i) * WW + col] = sg * conv;
        }
    }
}

extern "C" void kernel_launch(void* const* d_in, const int* in_sizes, int n_in,
                              void* d_out, int out_size, void* d_ws, size_t ws_size,
                              hipStream_t stream) {
    const float* x      = (const float*)d_in[0];
    const float* weight = (const float*)d_in[1];
    const float* conv_w = (const float*)d_in[2];
    const float* conv_b = (const float*)d_in[3];
    float* out = (float*)d_out;

    dim3 grid(HH / TH, NB, COUT / CPT);   // 8 x 4 x 32 = 1024 blocks
    aeg_conv_kernel<<<grid, 256, 0, stream>>>(x, weight, conv_w, conv_b, out);
}

// Round 22
// 33.027 us; speedup vs baseline: 1.3344x; 1.0166x over previous
//
#include <hip/hip_runtime.h>

#define CIN   32
#define COUT  64
#define HH    64
#define WW    64
#define NB    4
#define TH    16             // rows per block (512 threads, 8 waves)
#define HR    (TH + 2)       // 18 staged rows
#define G     8              // input channels per LDS round
#define CPT   2              // output channels per thread
#define ROWCI 72             // dwords per (row, ci): two 36-dword parity arrays
// parity array layout (36 dwords): [0]=left halo (col -1), [1..32]=cols, [33]=right halo (col 64)
// packed weight LDS: sw[ci][36] = [A(co0) 9 | A(co1) 9 | C(co0) 9 | C(co1) 9]

// ---- VOP3P packed-f32 helpers (CDNA4: v_pk_* = 2 fp32 ops/inst) ----
__device__ __forceinline__ float2 pk_fma_(float2 a, float2 b, float2 c) {   // a*b+c per half
    float2 d;
    asm("v_pk_fma_f32 %0, %1, %2, %3" : "=v"(d) : "v"(a), "v"(b), "v"(c));
    return d;
}
__device__ __forceinline__ float2 pk_add_(float2 a, float2 b) {
    float2 d;
    asm("v_pk_add_f32 %0, %1, %2" : "=v"(d) : "v"(a), "v"(b));
    return d;
}
template<int HI>        // a * {b[HI],b[HI]} : broadcast one half of pair b via op_sel
__device__ __forceinline__ float2 pk_mul_sel(float2 a, float2 b) {
    float2 d;
    if (HI) asm("v_pk_mul_f32 %0, %1, %2 op_sel:[0,1] op_sel_hi:[1,1]" : "=v"(d) : "v"(a), "v"(b));
    else    asm("v_pk_mul_f32 %0, %1, %2 op_sel:[0,0] op_sel_hi:[1,0]" : "=v"(d) : "v"(a), "v"(b));
    return d;
}
template<int HI>        // a * {b[HI],b[HI]} + c
__device__ __forceinline__ float2 pk_fma_sel(float2 a, float2 b, float2 c) {
    float2 d;
    if (HI) asm("v_pk_fma_f32 %0, %1, %2, %3 op_sel:[0,1,0] op_sel_hi:[1,1,1]" : "=v"(d) : "v"(a), "v"(b), "v"(c));
    else    asm("v_pk_fma_f32 %0, %1, %2, %3 op_sel:[0,0,0] op_sel_hi:[1,0,1]" : "=v"(d) : "v"(a), "v"(b), "v"(c));
    return d;
}

template<int S>
__device__ __forceinline__ void math_g(const float* __restrict__ sx,
                                       const float* __restrict__ sw,
                                       int lrow, int m, int cb, int g,
                                       float2 aeg2[CPT], float2 cv2[CPT])
{
    #pragma unroll 2
    for (int cl = 0; cl < G; ++cl) {
        const int ci = g + cl;
        // 15 taps: 5 window rows x (center b32 + side pair -> ds_read2_b32)
        float tc[5], tl[5], tr[5];
        #pragma unroll
        for (int wr = 0; wr < 5; ++wr) {
            const int qc = (wr & 1) ^ 1 ^ S;              // compile-time array select
            const float* rowp = sx + (lrow + wr) * (G * ROWCI) + cl * ROWCI;
            tc[wr] = rowp[qc * 36 + 1 + m];
            const float* sp = rowp + (1 - qc) * 36 + m + cb;
            tl[wr] = sp[0];
            tr[wr] = sp[1];
        }
        // pixel-pair taps: lo = p0 (window rows 0..2), hi = p1 (window rows 2..4)
        float2 t2c[3], t2l[3], t2r[3];
        #pragma unroll
        for (int wr = 0; wr < 3; ++wr) {
            t2c[wr] = make_float2(tc[wr], tc[wr + 2]);
            t2l[wr] = make_float2(tl[wr], tl[wr + 2]);
            t2r[wr] = make_float2(tr[wr], tr[wr + 2]);
        }

        // packed weights: 9 x ds_read_b128 broadcast; view as float2 pairs for op_sel
        float w[36];
        const float* pw = sw + ci * 36;
        #pragma unroll
        for (int u = 0; u < 9; ++u)
            *(float4*)&w[4 * u] = *(const float4*)&pw[4 * u];
        const float2* w2 = (const float2*)w;

        #pragma unroll
        for (int c = 0; c < CPT; ++c) {
            float2 r2 = make_float2(0.0f, 0.0f);
            #pragma unroll
            for (int k = 0; k < 9; ++k) {
                const int wr = k / 3;
                const int kj = k % 3;
                const float2 t2 = (kj == 0) ? t2l[wr] : ((kj == 1) ? t2c[wr] : t2r[wr]);
                const int ia = c * 9 + k;           // wA[k] at w2[ia/2][ia&1]
                const int ic = 18 + c * 9 + k;      // wC[k]
                float2 prod = (ia & 1) ? pk_mul_sel<1>(t2, w2[ia / 2])
                                       : pk_mul_sel<0>(t2, w2[ia / 2]);
                // pixel parity == S -> step parity = S^(k&1); even: r=(r+t)*y = r*y+prod
                //                                             odd : r=(r+y)*t = r*t+prod
                if ((k & 1) == S)
                    r2 = (ia & 1) ? pk_fma_sel<1>(r2, w2[ia / 2], prod)
                                  : pk_fma_sel<0>(r2, w2[ia / 2], prod);
                else
                    r2 = pk_fma_(r2, t2, prod);
                cv2[c] = (ic & 1) ? pk_fma_sel<1>(t2, w2[ic / 2], cv2[c])
                                  : pk_fma_sel<0>(t2, w2[ic / 2], cv2[c]);
            }
            aeg2[c] = pk_add_(aeg2[c], r2);
        }
    }
}

__global__ __launch_bounds__(512, 4)
void aeg_conv_kernel(const float* __restrict__ x,
                     const float* __restrict__ weight,
                     const float* __restrict__ conv_w,
                     const float* __restrict__ conv_b,
                     float* __restrict__ out)
{
    __shared__ float sx[HR * G * ROWCI];          // 18*8*72*4 = 41472 B
    __shared__ float sw[CIN * 36];                // 32*36*4   = 4608 B

    const int tid = threadIdx.x;
    const int i0  = blockIdx.x * TH;
    const int n   = blockIdx.y;
    const int co0 = blockIdx.z * CPT;

    const int s  = (tid >> 6) & 1;      // wave parity class (wave-uniform)
    const int rg = tid >> 7;            // row group (0..3)
    const int h  = (tid >> 5) & 1;      // half-wave -> row offset
    const int m  = tid & 31;

    const int rb_local = rg * 4 + h;            // local first pixel row: {0,1,4,5,8,9,12,13}; owns +0,+2
    const int rb  = i0 + rb_local;              // absolute first pixel row
    const int cb  = (rb & 1) ^ s;               // column LSB for this lane's class
    const int col = 2 * m + cb;                 // owned column (both pixel rows)

    const float* xn = x + (size_t)n * (CIN * HH * WW);

    // ---- zero the halo-column slots (0 and 33) of every parity array, once ----
    for (int idx = tid; idx < HR * G * 2 * 2; idx += 512) {
        int arr  = idx >> 1;                    // 0..287
        int slot = (idx & 1) ? 33 : 0;
        sx[arr * 36 + slot] = 0.0f;
    }

    // ---- stage packed weight slice into LDS: [ci][A0|A1|C0|C1] ----
    for (int idx = tid; idx < CIN * 36; idx += 512) {
        int ci = idx / 36, slot = idx - ci * 36;
        int set = slot / 18, rem = slot - set * 18;
        int c2 = rem / 9, k = rem - c2 * 9;
        const float* src = set ? conv_w : weight;
        sw[idx] = src[((size_t)(co0 + c2) * CIN + ci) * 9 + k];
    }

    float2 aeg2[CPT], cv2[CPT];
    #pragma unroll
    for (int c = 0; c < CPT; ++c) {
        aeg2[c] = make_float2(0.0f, 0.0f);
        cv2[c]  = make_float2(0.0f, 0.0f);
    }

    for (int g = 0; g < CIN; g += G) {
        __syncthreads();                // previous readers done (also covers init writes)
        // ---- stage HR rows x G ci, parity-split: scalar b32 stores (known-good) ----
        #pragma unroll
        for (int it = 0; it < 5; ++it) {
            int idx = it * 512 + tid;           // 0..2559, need 2304
            if (idx < HR * G * 16) {
                int f4   = idx & 15;            // 16B chunk within row
                int pair = idx >> 4;            // r18*G + cl, 0..143
                int r18  = pair >> 3;
                int cl   = pair & 7;
                int gi   = i0 - 1 + r18;
                float4 v = make_float4(0.f, 0.f, 0.f, 0.f);
                if ((unsigned)gi < (unsigned)HH)
                    v = *(const float4*)&xn[(g + cl) * (HH * WW) + gi * WW + 4 * f4];
                int rp   = gi & 1;              // parity array holding even cols
                float* base = &sx[pair * ROWCI];
                base[rp * 36 + 1 + 2 * f4]        = v.x;   // col 4f4
                base[rp * 36 + 2 + 2 * f4]        = v.z;   // col 4f4+2
                base[(rp ^ 1) * 36 + 1 + 2 * f4]  = v.y;   // col 4f4+1
                base[(rp ^ 1) * 36 + 2 + 2 * f4]  = v.w;   // col 4f4+3
            }
        }
        __syncthreads();

        if (s == 0) math_g<0>(sx, sw, rb_local, m, cb, g, aeg2, cv2);
        else        math_g<1>(sx, sw, rb_local, m, cb, g, aeg2, cv2);
    }

    // ---- epilogue: sigmoid(aeg) * (conv + bias) ----
    #pragma unroll
    for (int p = 0; p < 2; ++p) {
        int i = rb + 2 * p;
        #pragma unroll
        for (int c = 0; c < CPT; ++c) {
            int co = co0 + c;
            float a = p ? aeg2[c].y : aeg2[c].x;
            float v = p ? cv2[c].y  : cv2[c].x;
            float conv = v + conv_b[co];
            float sg = 1.0f / (1.0f + __expf(-a));
            out[(((size_t)n * COUT + co) * HH + i) * WW + col] = sg * conv;
        }
    }
}

extern "C" void kernel_launch(void* const* d_in, const int* in_sizes, int n_in,
                              void* d_out, int out_size, void* d_ws, size_t ws_size,
                              hipStream_t stream) {
    const float* x      = (const float*)d_in[0];
    const float* weight = (const float*)d_in[1];
    const float* conv_w = (const float*)d_in[2];
    const float* conv_b = (const float*)d_in[3];
    float* out = (float*)d_out;

    dim3 grid(HH / TH, NB, COUT / CPT);   // 4 x 4 x 32 = 512 blocks, 2 blocks/CU, 16 waves/CU
    aeg_conv_kernel<<<grid, 512, 0, stream>>>(x, weight, conv_w, conv_b, out);
}

// Round 23
// 32.406 us; speedup vs baseline: 1.3600x; 1.0192x over previous
//
#include <hip/hip_runtime.h>

#define CIN   32
#define COUT  64
#define HH    64
#define WW    64
#define NB    4
#define TH    16             // rows per block (512 threads, 8 waves)
#define HR    (TH + 2)       // 18 staged rows
#define G     8              // input channels per LDS round
#define CPT   2              // output channels per thread
#define ROWCI 72             // dwords per (row, ci): two 36-dword parity arrays
// parity array layout (36 dwords): [0]=left halo (col -1), [1..32]=cols, [33]=right halo (col 64)
// packed weight LDS: sw[ci][36] = [A(co0) 9 | A(co1) 9 | C(co0) 9 | C(co1) 9]

// ---- VOP3P packed-f32 helpers (CDNA4: v_pk_* = 2 fp32 ops/inst) ----
__device__ __forceinline__ float2 pk_fma_(float2 a, float2 b, float2 c) {   // a*b+c per half
    float2 d;
    asm("v_pk_fma_f32 %0, %1, %2, %3" : "=v"(d) : "v"(a), "v"(b), "v"(c));
    return d;
}
__device__ __forceinline__ float2 pk_add_(float2 a, float2 b) {
    float2 d;
    asm("v_pk_add_f32 %0, %1, %2" : "=v"(d) : "v"(a), "v"(b));
    return d;
}
template<int HI>        // a * {b[HI],b[HI]} : broadcast one half of pair b via op_sel
__device__ __forceinline__ float2 pk_mul_sel(float2 a, float2 b) {
    float2 d;
    if (HI) asm("v_pk_mul_f32 %0, %1, %2 op_sel:[0,1] op_sel_hi:[1,1]" : "=v"(d) : "v"(a), "v"(b));
    else    asm("v_pk_mul_f32 %0, %1, %2 op_sel:[0,0] op_sel_hi:[1,0]" : "=v"(d) : "v"(a), "v"(b));
    return d;
}
template<int HI>        // a * {b[HI],b[HI]} + c
__device__ __forceinline__ float2 pk_fma_sel(float2 a, float2 b, float2 c) {
    float2 d;
    if (HI) asm("v_pk_fma_f32 %0, %1, %2, %3 op_sel:[0,1,0] op_sel_hi:[1,1,1]" : "=v"(d) : "v"(a), "v"(b), "v"(c));
    else    asm("v_pk_fma_f32 %0, %1, %2, %3 op_sel:[0,0,0] op_sel_hi:[1,0,1]" : "=v"(d) : "v"(a), "v"(b), "v"(c));
    return d;
}

template<int S>
__device__ __forceinline__ void math_g(const float* __restrict__ sx,
                                       const float* __restrict__ sw,
                                       int lrow, int m, int cb, int g,
                                       float2 aeg2[CPT], float2 cv2[CPT])
{
    #pragma unroll 4
    for (int cl = 0; cl < G; ++cl) {
        const int ci = g + cl;
        // 15 taps: 5 window rows x (center b32 + side pair -> ds_read2_b32)
        float tc[5], tl[5], tr[5];
        #pragma unroll
        for (int wr = 0; wr < 5; ++wr) {
            const int qc = (wr & 1) ^ 1 ^ S;              // compile-time array select
            const float* rowp = sx + (lrow + wr) * (G * ROWCI) + cl * ROWCI;
            tc[wr] = rowp[qc * 36 + 1 + m];
            const float* sp = rowp + (1 - qc) * 36 + m + cb;
            tl[wr] = sp[0];
            tr[wr] = sp[1];
        }
        // pixel-pair taps: lo = p0 (window rows 0..2), hi = p1 (window rows 2..4)
        float2 t2c[3], t2l[3], t2r[3];
        #pragma unroll
        for (int wr = 0; wr < 3; ++wr) {
            t2c[wr] = make_float2(tc[wr], tc[wr + 2]);
            t2l[wr] = make_float2(tl[wr], tl[wr + 2]);
            t2r[wr] = make_float2(tr[wr], tr[wr + 2]);
        }

        // packed weights: 9 x ds_read_b128 broadcast; view as float2 pairs for op_sel
        float w[36];
        const float* pw = sw + ci * 36;
        #pragma unroll
        for (int u = 0; u < 9; ++u)
            *(float4*)&w[4 * u] = *(const float4*)&pw[4 * u];
        const float2* w2 = (const float2*)w;

        #pragma unroll
        for (int c = 0; c < CPT; ++c) {
            float2 r2 = make_float2(0.0f, 0.0f);
            #pragma unroll
            for (int k = 0; k < 9; ++k) {
                const int wr = k / 3;
                const int kj = k % 3;
                const float2 t2 = (kj == 0) ? t2l[wr] : ((kj == 1) ? t2c[wr] : t2r[wr]);
                const int ia = c * 9 + k;           // wA[k] at w2[ia/2][ia&1]
                const int ic = 18 + c * 9 + k;      // wC[k]
                float2 prod = (ia & 1) ? pk_mul_sel<1>(t2, w2[ia / 2])
                                       : pk_mul_sel<0>(t2, w2[ia / 2]);
                // pixel parity == S -> step parity = S^(k&1); even: r=(r+t)*y = r*y+prod
                //                                             odd : r=(r+y)*t = r*t+prod
                if ((k & 1) == S)
                    r2 = (ia & 1) ? pk_fma_sel<1>(r2, w2[ia / 2], prod)
                                  : pk_fma_sel<0>(r2, w2[ia / 2], prod);
                else
                    r2 = pk_fma_(r2, t2, prod);
                cv2[c] = (ic & 1) ? pk_fma_sel<1>(t2, w2[ic / 2], cv2[c])
                                  : pk_fma_sel<0>(t2, w2[ic / 2], cv2[c]);
            }
            aeg2[c] = pk_add_(aeg2[c], r2);
        }
    }
}

__global__ __launch_bounds__(512, 4)
void aeg_conv_kernel(const float* __restrict__ x,
                     const float* __restrict__ weight,
                     const float* __restrict__ conv_w,
                     const float* __restrict__ conv_b,
                     float* __restrict__ out)
{
    __shared__ float sx[HR * G * ROWCI];          // 18*8*72*4 = 41472 B
    __shared__ float sw[CIN * 36];                // 32*36*4   = 4608 B

    const int tid = threadIdx.x;
    const int i0  = blockIdx.x * TH;
    const int n   = blockIdx.y;
    const int co0 = blockIdx.z * CPT;

    const int s  = (tid >> 6) & 1;      // wave parity class (wave-uniform)
    const int rg = tid >> 7;            // row group (0..3)
    const int h  = (tid >> 5) & 1;      // half-wave -> row offset
    const int m  = tid & 31;

    const int rb_local = rg * 4 + h;            // local first pixel row: {0,1,4,5,8,9,12,13}; owns +0,+2
    const int rb  = i0 + rb_local;              // absolute first pixel row
    const int cb  = (rb & 1) ^ s;               // column LSB for this lane's class
    const int col = 2 * m + cb;                 // owned column (both pixel rows)

    const float* xn = x + (size_t)n * (CIN * HH * WW);

    // ---- zero the halo-column slots (0 and 33) of every parity array, once ----
    for (int idx = tid; idx < HR * G * 2 * 2; idx += 512) {
        int arr  = idx >> 1;                    // 0..287
        int slot = (idx & 1) ? 33 : 0;
        sx[arr * 36 + slot] = 0.0f;
    }

    // ---- stage packed weight slice into LDS: [ci][A0|A1|C0|C1] ----
    for (int idx = tid; idx < CIN * 36; idx += 512) {
        int ci = idx / 36, slot = idx - ci * 36;
        int set = slot / 18, rem = slot - set * 18;
        int c2 = rem / 9, k = rem - c2 * 9;
        const float* src = set ? conv_w : weight;
        sw[idx] = src[((size_t)(co0 + c2) * CIN + ci) * 9 + k];
    }

    float2 aeg2[CPT], cv2[CPT];
    #pragma unroll
    for (int c = 0; c < CPT; ++c) {
        aeg2[c] = make_float2(0.0f, 0.0f);
        cv2[c]  = make_float2(0.0f, 0.0f);
    }

    for (int g = 0; g < CIN; g += G) {
        __syncthreads();                // previous readers done (also covers init writes)
        // ---- stage HR rows x G ci, parity-split: scalar b32 stores (known-good) ----
        #pragma unroll
        for (int it = 0; it < 5; ++it) {
            int idx = it * 512 + tid;           // 0..2559, need 2304
            if (idx < HR * G * 16) {
                int f4   = idx & 15;            // 16B chunk within row
                int pair = idx >> 4;            // r18*G + cl, 0..143
                int r18  = pair >> 3;
                int cl   = pair & 7;
                int gi   = i0 - 1 + r18;
                float4 v = make_float4(0.f, 0.f, 0.f, 0.f);
                if ((unsigned)gi < (unsigned)HH)
                    v = *(const float4*)&xn[(g + cl) * (HH * WW) + gi * WW + 4 * f4];
                int rp   = gi & 1;              // parity array holding even cols
                float* base = &sx[pair * ROWCI];
                base[rp * 36 + 1 + 2 * f4]        = v.x;   // col 4f4
                base[rp * 36 + 2 + 2 * f4]        = v.z;   // col 4f4+2
                base[(rp ^ 1) * 36 + 1 + 2 * f4]  = v.y;   // col 4f4+1
                base[(rp ^ 1) * 36 + 2 + 2 * f4]  = v.w;   // col 4f4+3
            }
        }
        __syncthreads();

        if (s == 0) math_g<0>(sx, sw, rb_local, m, cb, g, aeg2, cv2);
        else        math_g<1>(sx, sw, rb_local, m, cb, g, aeg2, cv2);
    }

    // ---- epilogue: sigmoid(aeg) * (conv + bias) ----
    #pragma unroll
    for (int p = 0; p < 2; ++p) {
        int i = rb + 2 * p;
        #pragma unroll
        for (int c = 0; c < CPT; ++c) {
            int co = co0 + c;
            float a = p ? aeg2[c].y : aeg2[c].x;
            float v = p ? cv2[c].y  : cv2[c].x;
            float conv = v + conv_b[co];
            float sg = 1.0f / (1.0f + __expf(-a));
            out[(((size_t)n * COUT + co) * HH + i) * WW + col] = sg * conv;
        }
    }
}

extern "C" void kernel_launch(void* const* d_in, const int* in_sizes, int n_in,
                              void* d_out, int out_size, void* d_ws, size_t ws_size,
                              hipStream_t stream) {
    const float* x      = (const float*)d_in[0];
    const float* weight = (const float*)d_in[1];
    const float* conv_w = (const float*)d_in[2];
    const float* conv_b = (const float*)d_in[3];
    float* out = (float*)d_out;

    dim3 grid(HH / TH, NB, COUT / CPT);   // 4 x 4 x 32 = 512 blocks, 2 blocks/CU, 16 waves/CU
    aeg_conv_kernel<<<grid, 512, 0, stream>>>(x, weight, conv_w, conv_b, out);
}